// Round 15
// baseline (5007.325 us; speedup 1.0000x reference)
//
#include <hip/hip_runtime.h>
#include <math.h>

#define H   512
#define B   512
#define T   512
#define TGT 28

typedef __bf16 bf16x8 __attribute__((ext_vector_type(8)));
typedef float  f32x4  __attribute__((ext_vector_type(4)));
typedef unsigned short u16;

// ws byte offsets
#define OFF_WPH  0x000000u  // Wpack_hi 2MB (frag-linear bf16)
#define OFF_WPL  0x200000u  // Wpack_lo 2MB
#define OFF_HHI0 0x400000u  // 512KB h hi buf0   (zeroed)
#define OFF_HLO0 0x480000u  // 512KB h lo buf0   (zeroed)
#define OFF_SYNC 0x500000u  // 4KB   sync page   (zeroed)
#define OFF_HHI1 0x501000u  // 512KB h hi buf1
#define OFF_HLO1 0x581000u  // 512KB h lo buf1

// v16: dynamic LDS = W-hi only (64KB). W-lo streams from L2 (own 64KB slice
// per CU; +15GB/s/CU of L2 reads ~ 11% of per-CU share — BW-trivial).
// Static: gA+gB[2][64][36] f32 = 36,864B + flags. Total ~102KB -> 1 WG/CU
// pigeonhole intact (2 WGs would need 204KB > 160KB).
#define SMEM_BYTES 65536

__device__ inline u16 f2bf(float x) {
    unsigned u = __builtin_bit_cast(unsigned, x);
    u += 0x7FFFu + ((u >> 16) & 1u);          // RNE
    return (u16)(u >> 16);
}
__device__ inline float bf2f(u16 h) {
    unsigned u = ((unsigned)h) << 16;
    return __builtin_bit_cast(float, u);
}
// fast activations (validated v5-v15: absmax 1.22e-4, = libm baseline)
__device__ inline float frcp(float x) {
    float r = __builtin_amdgcn_rcpf(x);
    return r * fmaf(-x, r, 2.0f);
}
__device__ inline float fsig(float x) {
    return frcp(1.0f + __expf(-x));
}
__device__ inline float ftanh(float x) {
    return fmaf(2.0f, fsig(2.0f * x), -1.0f);
}

// group barrier among 4 waves via LDS int flags (v13 mechanism, tripwired)
__device__ inline void group_barrier(int* gb, int kh, int l, int seq) {
    if (l == 0)
        __hip_atomic_store(&gb[kh], seq, __ATOMIC_RELEASE,
                           __HIP_MEMORY_SCOPE_WORKGROUP);
    int guard = 0;
    for (;;) {
        int v = __hip_atomic_load(&gb[l & 3], __ATOMIC_ACQUIRE,
                                  __HIP_MEMORY_SCOPE_WORKGROUP);
        if (__all(v >= seq)) break;
        if (++guard > (1 << 17)) break;       // tripwire: clean fail, no hang
    }
}

// ---------------------------------------------------------------------------
// Pack W_hh frag-linear bf16 hi/lo.  idx: r(5)|q(2)|S(4)|l(6), 8 k each.
// g = q*512 + r*16 + (l&15) ; k = S*32 + (l>>4)*8
// ---------------------------------------------------------------------------
__global__ __launch_bounds__(256) void init_pack(const float* __restrict__ Whh,
                                                 u16* __restrict__ wph,
                                                 u16* __restrict__ wpl) {
    int idx = blockIdx.x * 256 + threadIdx.x;   // [0, 131072)
    int l  = idx & 63;
    int S  = (idx >> 6) & 15;
    int q  = (idx >> 10) & 3;
    int r  = idx >> 12;
    int g  = q * 512 + r * 16 + (l & 15);
    int k  = S * 32 + ((l >> 4) * 8);
    const float* src = Whh + (size_t)g * H + k;
    __align__(16) u16 hi8[8];
    __align__(16) u16 lo8[8];
#pragma unroll
    for (int j = 0; j < 8; ++j) {
        float w = src[j];
        u16 hb = f2bf(w);
        hi8[j] = hb;
        lo8[j] = f2bf(w - bf2f(hb));
    }
    *(uint4*)(wph + (size_t)idx * 8) = *(const uint4*)hi8;
    *(uint4*)(wpl + (size_t)idx * 8) = *(const uint4*)lo8;
}

// zero [OFF_HHI0, OFF_HHI1) = h buf0 hi/lo + sync page = 263168 dwords
__global__ __launch_bounds__(256) void init_state(unsigned* __restrict__ zbase) {
    int idx = blockIdx.x * 256 + threadIdx.x;
    if (idx < 263168) zbase[idx] = 0u;
}

// ---------------------------------------------------------------------------
// Persistent XCD-local LSTM, v16 = v13/v15 structure (best passing, 4175us;
// anti-phase stagger dropped — v15 proved it null) + ONE coherent structural
// change to the reduce critical path:
//  (1) W-lo streams from L2 (frees 64KB LDS; removes 16/32 ds_read_b128 per
//      wave -> halves LDS B-path pressure; verification: bank-conflict drop)
//  (2) TREE REDUCE in the freed LDS: two buffers/group. R1: kh0->gA || kh2->gB
//      (write, disjoint). GB. R2: kh1 RMW gA || kh3 RMW gB. GB. Cell reads
//      gA+gB.  4 rounds+4 barriers -> 2+2, 2x wave activity per round.
//      Regroup (kh0+kh1)+(kh2+kh3): drift << threshold.
//  (3) s_sleep(2) in the grel poll — stop the waiting group's 7 waves from
//      flooding the LDS pipe with busy-spin loads while the other group works.
// XCD protocol byte-identical to v13 (per-group counters 128B apart).
// ---------------------------------------------------------------------------
__global__ __launch_bounds__(512, 1) void lstm_persistent(
    const u16* __restrict__ wph, const u16* __restrict__ wpl,
    u16* __restrict__ hhi0, u16* __restrict__ hlo0,
    u16* __restrict__ hhi1, u16* __restrict__ hlo1,
    int* __restrict__ sync, const float* __restrict__ seq,
    const float* __restrict__ Wih, const float* __restrict__ bih,
    const float* __restrict__ bhh)
{
    extern __shared__ char smem[];
    u16* wh = (u16*)smem;                          // 64KB W-hi
    __shared__ __align__(16) float gA[2][64][36];  // per-group tree buf A
    __shared__ __align__(16) float gB[2][64][36];  // per-group tree buf B
    __shared__ int gbar[2][4];                     // group barrier flags
    __shared__ int grel[2];                        // group release seq
    __shared__ int sh_pr[2];

    const int tid = threadIdx.x;
    const int l   = tid & 63;
    const int w   = tid >> 6;
    const int g   = w >> 2;                        // group 0/1 (row half)
    const int kh  = w & 3;                         // K-quarter 0..3

    // ---- partition assignment: physical XCD id + per-XCD slot ----
    if (tid == 0) {
        unsigned xcc;
        asm volatile("s_getreg_b32 %0, hwreg(HW_REG_XCC_ID)" : "=s"(xcc));
        int p = (int)(xcc & 7u);
        int r = __hip_atomic_fetch_add(&sync[p * 32], 1,
                                       __ATOMIC_RELAXED, __HIP_MEMORY_SCOPE_AGENT);
        sh_pr[0] = p;
        sh_pr[1] = r & 31;                         // 0..31 (pigeonhole: 1 WG/CU)
    }
    if (tid < 8) gbar[tid >> 2][tid & 3] = 0;
    if (tid < 2) grel[tid] = 0;
    __syncthreads();                               // prologue only
    const int p = sh_pr[0];
    const int r = sh_pr[1];
    int* arrp = &sync[256 + p * 64 + g * 32];      // per-GROUP counter, own line
    int* gb   = gbar[g];

    // ---- stage W-hi slice (worker r) into LDS, once, all 512 threads ----
    {
        const uint4* gh = (const uint4*)(wph + (size_t)r * 32768);
        uint4* sh = (uint4*)wh;
#pragma unroll
        for (int i = 0; i < 8; ++i) {
            int idx = tid + i * 512;               // 0..4095
            sh[idx] = gh[idx];
        }
    }
    const u16* glo = wpl + (size_t)r * 32768;      // W-lo slice: L2-resident

    // ---- thread-resident cell constants (group-local thread index) ----
    const int lt   = tid & 255;                    // 0..255 within group
    const int cc   = lt & 15;
    const int m0   = lt >> 4;                      // 0..15
    const int kcol = r * 16 + cc;
    float wib[4], bb[4];
#pragma unroll
    for (int q = 0; q < 4; ++q) {
        int gg = q * 512 + kcol;
        wib[q] = Wih[gg];
        bb[q]  = bih[gg] + bhh[gg];
    }
    float cr0 = 0.0f, cr1 = 0.0f;
    const int pb = p * 64;
    const int b0 = pb + g * 32 + m0;               // group rows
    const int b1 = b0 + 16;

    const int arow0 = (pb + g * 32 + (l & 15)) * H;
    const int arow1 = arow0 + 16 * H;

    __syncthreads();                               // W staged (prologue only)

    for (int t = 0; t < T; ++t) {
        const u16* hih = (t & 1) ? hhi1 : hhi0;
        const u16* hil = (t & 1) ? hlo1 : hlo0;
        u16* hoh = (t & 1) ? hhi0 : hhi1;
        u16* hol = (t & 1) ? hlo0 : hlo1;

        float sv0 = seq[(size_t)b0 * T + t];
        float sv1 = seq[(size_t)b1 * T + t];

        f32x4 acc[2][4] = {};

        // ---- MFMA phase: rolled s-loop; bh from LDS, bl from L2 ----
#pragma unroll 1
        for (int s = 0; s < 4; ++s) {
            const int S  = kh * 4 + s;
            const int ka = S * 32 + ((l >> 4) * 8);
            bf16x8 a0h = *(const bf16x8*)(hih + arow0 + ka);
            bf16x8 a1h = *(const bf16x8*)(hih + arow1 + ka);
            bf16x8 a0l = *(const bf16x8*)(hil + arow0 + ka);
            bf16x8 a1l = *(const bf16x8*)(hil + arow1 + ka);
#pragma unroll
            for (int n = 0; n < 4; ++n) {
                const int fo = ((n * 16 + S) * 64 + l) * 8;
                bf16x8 bh = *(const bf16x8*)(wh + fo);
                bf16x8 bl = *(const bf16x8*)(glo + fo);
                acc[0][n] = __builtin_amdgcn_mfma_f32_16x16x32_bf16(a0h, bh, acc[0][n], 0, 0, 0);
                acc[1][n] = __builtin_amdgcn_mfma_f32_16x16x32_bf16(a1h, bh, acc[1][n], 0, 0, 0);
                acc[0][n] = __builtin_amdgcn_mfma_f32_16x16x32_bf16(a0h, bl, acc[0][n], 0, 0, 0);
                acc[1][n] = __builtin_amdgcn_mfma_f32_16x16x32_bf16(a1h, bl, acc[1][n], 0, 0, 0);
                acc[0][n] = __builtin_amdgcn_mfma_f32_16x16x32_bf16(a0l, bh, acc[0][n], 0, 0, 0);
                acc[1][n] = __builtin_amdgcn_mfma_f32_16x16x32_bf16(a1l, bh, acc[1][n], 0, 0, 0);
            }
        }

        // ---- TREE reduce, 2 rounds, group-local barriers ----
        // D: col=lane&15 -> n2, row=(lane>>4)*4+reg -> m (4 consecutive).
        const int base = t * 3;
        if (kh == 0 || kh == 2) {                  // round 1: disjoint writes
            float (*gt)[36] = (kh == 0) ? gA[g] : gB[g];
#pragma unroll
            for (int ms = 0; ms < 2; ++ms)
#pragma unroll
                for (int n = 0; n < 4; ++n) {
                    const int n2 = n * 16 + (l & 15);
                    const int mb = ms * 16 + ((l >> 4) << 2);
                    *(f32x4*)&gt[n2][mb] = acc[ms][n];
                }
        }
        group_barrier(gb, kh, l, base + 1);
        if (kh == 1 || kh == 3) {                  // round 2: disjoint RMW
            float (*gt)[36] = (kh == 1) ? gA[g] : gB[g];
#pragma unroll
            for (int ms = 0; ms < 2; ++ms)
#pragma unroll
                for (int n = 0; n < 4; ++n) {
                    const int n2 = n * 16 + (l & 15);
                    const int mb = ms * 16 + ((l >> 4) << 2);
                    float* gp = &gt[n2][mb];
                    f32x4 v = *(const f32x4*)gp;
                    v += acc[ms][n];
                    *(f32x4*)gp = v;
                }
        }
        group_barrier(gb, kh, l, base + 2);

        // ---- cell update: 2 cells/thread, gates = gA + gB ----
        {
            float pre[4];
#pragma unroll
            for (int q = 0; q < 4; ++q)
                pre[q] = gA[g][q * 16 + cc][m0] + gB[g][q * 16 + cc][m0]
                       + fmaf(sv0, wib[q], bb[q]);
            float ig = fsig(pre[0]);
            float fg = fsig(pre[1]);
            float gg2 = ftanh(pre[2]);
            float og = fsig(pre[3]);
            cr0 = fg * cr0 + ig * gg2;
            float hv = og * ftanh(cr0);
            u16 hb = f2bf(hv);
            size_t ci = (size_t)b0 * H + kcol;
            hoh[ci] = hb;
            hol[ci] = f2bf(hv - bf2f(hb));
        }
        {
            float pre[4];
#pragma unroll
            for (int q = 0; q < 4; ++q)
                pre[q] = gA[g][q * 16 + cc][m0 + 16] + gB[g][q * 16 + cc][m0 + 16]
                       + fmaf(sv1, wib[q], bb[q]);
            float ig = fsig(pre[0]);
            float fg = fsig(pre[1]);
            float gg2 = ftanh(pre[2]);
            float og = fsig(pre[3]);
            cr1 = fg * cr1 + ig * gg2;
            float hv = og * ftanh(cr1);
            u16 hb = f2bf(hv);
            size_t ci = (size_t)b1 * H + kcol;
            hoh[ci] = hb;
            hol[ci] = f2bf(hv - bf2f(hb));
        }

        // ---- per-GROUP XCD barrier (v13 protocol; skip after last step) ----
        if (t < T - 1) {
            asm volatile("s_waitcnt vmcnt(0)" ::: "memory");  // own h stores in L2
            group_barrier(gb, kh, l, base + 3);               // group drained
            if (kh == 0 && l == 0) {
                __hip_atomic_fetch_add(arrp, 1, __ATOMIC_RELAXED,
                                       __HIP_MEMORY_SCOPE_AGENT);
                const int target = 32 * (t + 1);
                int guard = 0;
                while (__hip_atomic_load(arrp, __ATOMIC_RELAXED,
                                         __HIP_MEMORY_SCOPE_AGENT) < target) {
                    __builtin_amdgcn_s_sleep(1);
                    if (++guard > (1 << 18)) break;           // tripwire
                }
                __hip_atomic_store(&grel[g], t + 1, __ATOMIC_RELEASE,
                                   __HIP_MEMORY_SCOPE_WORKGROUP);
            }
            {
                int guard = 0;
                while (__hip_atomic_load(&grel[g], __ATOMIC_ACQUIRE,
                                         __HIP_MEMORY_SCOPE_WORKGROUP) < t + 1) {
                    __builtin_amdgcn_s_sleep(2);              // free LDS pipe
                    if (++guard > (1 << 16)) break;           // tripwire
                }
            }
            asm volatile("buffer_inv sc0" ::: "memory");      // invalidate L1 only
        }
    }
}

// ---------------------------------------------------------------------------
// MLP head
// ---------------------------------------------------------------------------
__global__ __launch_bounds__(256) void head_kernel(const u16* __restrict__ hhi,
                                                   const u16* __restrict__ hlo,
                                                   const float* __restrict__ fc1w,
                                                   const float* __restrict__ fc1b,
                                                   const float* __restrict__ fc2w,
                                                   const float* __restrict__ fc2b,
                                                   float* __restrict__ out) {
    const int b = blockIdx.x;
    const int tid = threadIdx.x;
    __shared__ __align__(16) float hb[H];
    __shared__ float z[256];

    hb[tid]       = bf2f(hhi[(size_t)b * H + tid])       + bf2f(hlo[(size_t)b * H + tid]);
    hb[tid + 256] = bf2f(hhi[(size_t)b * H + tid + 256]) + bf2f(hlo[(size_t)b * H + tid + 256]);
    __syncthreads();

    float acc = fc1b[tid];
    const float4* wr = (const float4*)(fc1w + (size_t)tid * H);
    const float4* hr = (const float4*)hb;
#pragma unroll 4
    for (int kk = 0; kk < H / 4; ++kk) {
        float4 wv = wr[kk], hv = hr[kk];
        acc += wv.x * hv.x + wv.y * hv.y + wv.z * hv.z + wv.w * hv.w;
    }
    z[tid] = fmaxf(acc, 0.0f);
    __syncthreads();

    if (tid < TGT) {
        float a = fc2b[tid];
        const float* w2 = fc2w + (size_t)tid * 256;
#pragma unroll 8
        for (int j = 0; j < 256; ++j) a += z[j] * w2[j];
        out[(size_t)b * TGT + tid] = a;
    }
}

extern "C" void kernel_launch(void* const* d_in, const int* in_sizes, int n_in,
                              void* d_out, int out_size, void* d_ws, size_t ws_size,
                              hipStream_t stream) {
    const float* seq  = (const float*)d_in[0];
    const float* Wih  = (const float*)d_in[1];
    const float* Whh  = (const float*)d_in[2];
    const float* bih  = (const float*)d_in[3];
    const float* bhh  = (const float*)d_in[4];
    const float* fc1w = (const float*)d_in[5];
    const float* fc1b = (const float*)d_in[6];
    const float* fc2w = (const float*)d_in[7];
    const float* fc2b = (const float*)d_in[8];
    float* out = (float*)d_out;

    char* wsb = (char*)d_ws;
    u16* wph  = (u16*)(wsb + OFF_WPH);
    u16* wpl  = (u16*)(wsb + OFF_WPL);
    u16* hhi0 = (u16*)(wsb + OFF_HHI0);
    u16* hlo0 = (u16*)(wsb + OFF_HLO0);
    u16* hhi1 = (u16*)(wsb + OFF_HHI1);
    u16* hlo1 = (u16*)(wsb + OFF_HLO1);
    int* sync = (int*)(wsb + OFF_SYNC);

    init_pack<<<512, 256, 0, stream>>>(Whh, wph, wpl);
    init_state<<<1028, 256, 0, stream>>>((unsigned*)(wsb + OFF_HHI0));

    hipFuncSetAttribute((const void*)lstm_persistent,
                        hipFuncAttributeMaxDynamicSharedMemorySize, SMEM_BYTES);

    void* args[] = {(void*)&wph, (void*)&wpl, (void*)&hhi0, (void*)&hlo0,
                    (void*)&hhi1, (void*)&hlo1, (void*)&sync, (void*)&seq,
                    (void*)&Wih, (void*)&bih, (void*)&bhh};
    // proven launch shape: 256 WGs x 512 thr, 1 WG/CU
    hipLaunchCooperativeKernel((const void*)lstm_persistent, dim3(256), dim3(512),
                               args, SMEM_BYTES, stream);

    // T even -> final h in buffer 0
    head_kernel<<<B, 256, 0, stream>>>(hhi0, hlo0, fc1w, fc1b, fc2w, fc2b, out);
}

// Round 16
// 4422.395 us; speedup vs baseline: 1.1323x; 1.1323x over previous
//
#include <hip/hip_runtime.h>
#include <math.h>

#define H   512
#define B   512
#define T   512
#define TGT 28

typedef __bf16 bf16x8 __attribute__((ext_vector_type(8)));
typedef float  f32x4  __attribute__((ext_vector_type(4)));
typedef unsigned short u16;

// ws byte offsets
#define OFF_WPH  0x000000u  // Wpack_hi 2MB (frag-linear bf16)
#define OFF_WPL  0x200000u  // Wpack_lo 2MB
#define OFF_HHI0 0x400000u  // 512KB h hi buf0   (zeroed)
#define OFF_HLO0 0x480000u  // 512KB h lo buf0   (zeroed)
#define OFF_SYNC 0x500000u  // 4KB   sync page   (zeroed)
#define OFF_HHI1 0x501000u  // 512KB h hi buf1
#define OFF_HLO1 0x581000u  // 512KB h lo buf1

// v17: dynamic LDS = W-hi only (64KB). W-lo lives in REGISTERS (16 bf16x8 =
// 64 VGPR/lane, loop-carried via asm pin). Static: gatesT[2][64][36] f32
// (18432B) + flags. ~84KB/WG -> 2 WGs would need 168KB > 160KB -> pigeonhole
// (exactly 1 WG/CU) intact. W-lo is read from global ONCE (no L2 streaming —
// v16 post-mortem: per-step W L2 traffic evicted dirty h lines -> 532MB HBM
// writeback storm).
#define SMEM_BYTES 65536

__device__ inline u16 f2bf(float x) {
    unsigned u = __builtin_bit_cast(unsigned, x);
    u += 0x7FFFu + ((u >> 16) & 1u);          // RNE
    return (u16)(u >> 16);
}
__device__ inline float bf2f(u16 h) {
    unsigned u = ((unsigned)h) << 16;
    return __builtin_bit_cast(float, u);
}
// fast activations (validated v5-v15: absmax 1.22e-4, = libm baseline)
__device__ inline float frcp(float x) {
    float r = __builtin_amdgcn_rcpf(x);
    return r * fmaf(-x, r, 2.0f);
}
__device__ inline float fsig(float x) {
    return frcp(1.0f + __expf(-x));
}
__device__ inline float ftanh(float x) {
    return fmaf(2.0f, fsig(2.0f * x), -1.0f);
}

// group barrier among 4 waves via LDS int flags (v13 mechanism, tripwired)
__device__ inline void group_barrier(int* gb, int kh, int l, int seq) {
    if (l == 0)
        __hip_atomic_store(&gb[kh], seq, __ATOMIC_RELEASE,
                           __HIP_MEMORY_SCOPE_WORKGROUP);
    int guard = 0;
    for (;;) {
        int v = __hip_atomic_load(&gb[l & 3], __ATOMIC_ACQUIRE,
                                  __HIP_MEMORY_SCOPE_WORKGROUP);
        if (__all(v >= seq)) break;
        if (++guard > (1 << 17)) break;       // tripwire: clean fail, no hang
    }
}

// ---------------------------------------------------------------------------
// Pack W_hh frag-linear bf16 hi/lo.  idx: r(5)|q(2)|S(4)|l(6), 8 k each.
// g = q*512 + r*16 + (l&15) ; k = S*32 + (l>>4)*8
// ---------------------------------------------------------------------------
__global__ __launch_bounds__(256) void init_pack(const float* __restrict__ Whh,
                                                 u16* __restrict__ wph,
                                                 u16* __restrict__ wpl) {
    int idx = blockIdx.x * 256 + threadIdx.x;   // [0, 131072)
    int l  = idx & 63;
    int S  = (idx >> 6) & 15;
    int q  = (idx >> 10) & 3;
    int r  = idx >> 12;
    int g  = q * 512 + r * 16 + (l & 15);
    int k  = S * 32 + ((l >> 4) * 8);
    const float* src = Whh + (size_t)g * H + k;
    __align__(16) u16 hi8[8];
    __align__(16) u16 lo8[8];
#pragma unroll
    for (int j = 0; j < 8; ++j) {
        float w = src[j];
        u16 hb = f2bf(w);
        hi8[j] = hb;
        lo8[j] = f2bf(w - bf2f(hb));
    }
    *(uint4*)(wph + (size_t)idx * 8) = *(const uint4*)hi8;
    *(uint4*)(wpl + (size_t)idx * 8) = *(const uint4*)lo8;
}

// zero [OFF_HHI0, OFF_HHI1) = h buf0 hi/lo + sync page = 263168 dwords
__global__ __launch_bounds__(256) void init_state(unsigned* __restrict__ zbase) {
    int idx = blockIdx.x * 256 + threadIdx.x;
    if (idx < 263168) zbase[idx] = 0u;
}

// ---------------------------------------------------------------------------
// Persistent XCD-local LSTM, v17 = v13 structure (best passing, 4175us) +
// ONE change: W-LO IN REGISTERS, loop-carried.
//   Clock discovery (v16 post-mortem): MfmaUtil vs known MFMA cycles shows
//   the kernel runs at ~700MHz -> the LDS pipe (8 waves x 32 ds_read_b128
//   W-reads = 3072 cy/CU/step) is the DOMINANT cost (~4.4us of 8.46us/step).
//   Fix: each wave's 16 W-lo fragments (64 VGPR) are loaded from global ONCE
//   before the t-loop; an empty asm "+v" pin at the TOP of each iteration
//   makes them a loop-carried register dependency the compiler cannot
//   rematerialize (v3's failure mode) — and, being loop-invariant, the pin
//   adds no vmcnt drain (v8's failure mode). LDS W-reads: 32 -> 16 per wave.
//   s-loop re-unrolled for static wbl indexing (roll-vs-unroll neutral, v10).
//   MFMA order unchanged -> absmax exactly 1.2207e-4.
// ---------------------------------------------------------------------------
__global__ __launch_bounds__(512, 1) void lstm_persistent(
    const u16* __restrict__ wph, const u16* __restrict__ wpl,
    u16* __restrict__ hhi0, u16* __restrict__ hlo0,
    u16* __restrict__ hhi1, u16* __restrict__ hlo1,
    int* __restrict__ sync, const float* __restrict__ seq,
    const float* __restrict__ Wih, const float* __restrict__ bih,
    const float* __restrict__ bhh)
{
    extern __shared__ char smem[];
    u16* wh = (u16*)smem;                          // 64KB W-hi
    __shared__ __align__(16) float gatesT[2][64][36];  // per-group [n2][m]
    __shared__ int gbar[2][4];                     // group barrier flags
    __shared__ int grel[2];                        // group release seq
    __shared__ int sh_pr[2];

    const int tid = threadIdx.x;
    const int l   = tid & 63;
    const int w   = tid >> 6;
    const int g   = w >> 2;                        // group 0/1 (row half)
    const int kh  = w & 3;                         // K-quarter 0..3

    // ---- partition assignment: physical XCD id + per-XCD slot ----
    if (tid == 0) {
        unsigned xcc;
        asm volatile("s_getreg_b32 %0, hwreg(HW_REG_XCC_ID)" : "=s"(xcc));
        int p = (int)(xcc & 7u);
        int r = __hip_atomic_fetch_add(&sync[p * 32], 1,
                                       __ATOMIC_RELAXED, __HIP_MEMORY_SCOPE_AGENT);
        sh_pr[0] = p;
        sh_pr[1] = r & 31;                         // 0..31 (pigeonhole: 1 WG/CU)
    }
    if (tid < 8) gbar[tid >> 2][tid & 3] = 0;
    if (tid < 2) grel[tid] = 0;
    __syncthreads();                               // prologue only
    const int p = sh_pr[0];
    const int r = sh_pr[1];
    int* arrp = &sync[256 + p * 64 + g * 32];      // per-GROUP counter, own line
    int* gb   = gbar[g];

    // ---- stage W-hi slice (worker r) into LDS, once, all 512 threads ----
    {
        const uint4* gh = (const uint4*)(wph + (size_t)r * 32768);
        uint4* sh = (uint4*)wh;
#pragma unroll
        for (int i = 0; i < 8; ++i) {
            int idx = tid + i * 512;               // 0..4095
            sh[idx] = gh[idx];
        }
    }

    // ---- W-lo fragments into REGISTERS, once (16 x bf16x8 = 64 VGPR) ----
    bf16x8 wbl[16];
    {
        const u16* gl = wpl + (size_t)r * 32768;
#pragma unroll
        for (int s = 0; s < 4; ++s)
#pragma unroll
            for (int n = 0; n < 4; ++n)
                wbl[s * 4 + n] =
                    *(const bf16x8*)(gl + ((size_t)((n * 16 + kh * 4 + s) * 64 + l)) * 8);
    }

    // ---- thread-resident cell constants (group-local thread index) ----
    const int lt   = tid & 255;                    // 0..255 within group
    const int cc   = lt & 15;
    const int m0   = lt >> 4;                      // 0..15
    const int kcol = r * 16 + cc;
    float wib[4], bb[4];
#pragma unroll
    for (int q = 0; q < 4; ++q) {
        int gg = q * 512 + kcol;
        wib[q] = Wih[gg];
        bb[q]  = bih[gg] + bhh[gg];
    }
    float cr0 = 0.0f, cr1 = 0.0f;
    const int pb = p * 64;
    const int b0 = pb + g * 32 + m0;               // group rows
    const int b1 = b0 + 16;

    const int arow0 = (pb + g * 32 + (l & 15)) * H;
    const int arow1 = arow0 + 16 * H;

    __syncthreads();                               // W staged (prologue only)

    for (int t = 0; t < T; ++t) {
        // ---- loop-carried pin: wbl values are register-resident, period ----
        asm volatile(""
            : "+v"(wbl[0]), "+v"(wbl[1]), "+v"(wbl[2]),  "+v"(wbl[3]),
              "+v"(wbl[4]), "+v"(wbl[5]), "+v"(wbl[6]),  "+v"(wbl[7]),
              "+v"(wbl[8]), "+v"(wbl[9]), "+v"(wbl[10]), "+v"(wbl[11]),
              "+v"(wbl[12]), "+v"(wbl[13]), "+v"(wbl[14]), "+v"(wbl[15]));

        const u16* hih = (t & 1) ? hhi1 : hhi0;
        const u16* hil = (t & 1) ? hlo1 : hlo0;
        u16* hoh = (t & 1) ? hhi0 : hhi1;
        u16* hol = (t & 1) ? hlo0 : hlo1;

        float sv0 = seq[(size_t)b0 * T + t];
        float sv1 = seq[(size_t)b1 * T + t];

        f32x4 acc[2][4] = {};

        // ---- MFMA phase: unrolled s (static wbl index); bh from LDS ----
#pragma unroll
        for (int s = 0; s < 4; ++s) {
            const int S  = kh * 4 + s;
            const int ka = S * 32 + ((l >> 4) * 8);
            bf16x8 a0h = *(const bf16x8*)(hih + arow0 + ka);
            bf16x8 a1h = *(const bf16x8*)(hih + arow1 + ka);
            bf16x8 a0l = *(const bf16x8*)(hil + arow0 + ka);
            bf16x8 a1l = *(const bf16x8*)(hil + arow1 + ka);
#pragma unroll
            for (int n = 0; n < 4; ++n) {
                const int fo = ((n * 16 + S) * 64 + l) * 8;
                bf16x8 bh = *(const bf16x8*)(wh + fo);
                bf16x8 bl = wbl[s * 4 + n];
                acc[0][n] = __builtin_amdgcn_mfma_f32_16x16x32_bf16(a0h, bh, acc[0][n], 0, 0, 0);
                acc[1][n] = __builtin_amdgcn_mfma_f32_16x16x32_bf16(a1h, bh, acc[1][n], 0, 0, 0);
                acc[0][n] = __builtin_amdgcn_mfma_f32_16x16x32_bf16(a0h, bl, acc[0][n], 0, 0, 0);
                acc[1][n] = __builtin_amdgcn_mfma_f32_16x16x32_bf16(a1h, bl, acc[1][n], 0, 0, 0);
                acc[0][n] = __builtin_amdgcn_mfma_f32_16x16x32_bf16(a0l, bh, acc[0][n], 0, 0, 0);
                acc[1][n] = __builtin_amdgcn_mfma_f32_16x16x32_bf16(a1l, bh, acc[1][n], 0, 0, 0);
            }
        }

        // ---- K reduction, 4 rounds, GROUP-LOCAL barriers (order = v13) ----
        const int base = t * 5;
#pragma unroll
        for (int rr = 0; rr < 4; ++rr) {
            if (kh == rr) {
#pragma unroll
                for (int ms = 0; ms < 2; ++ms)
#pragma unroll
                    for (int n = 0; n < 4; ++n) {
                        const int n2 = n * 16 + (l & 15);
                        const int mb = ms * 16 + ((l >> 4) << 2);
                        float* gp = &gatesT[g][n2][mb];
                        if (rr == 0) {
                            *(f32x4*)gp = acc[ms][n];
                        } else {
                            f32x4 v = *(const f32x4*)gp;
                            v += acc[ms][n];
                            *(f32x4*)gp = v;
                        }
                    }
            }
            group_barrier(gb, kh, l, base + rr + 1);
        }

        // ---- cell update: 2 cells/thread, c in registers, fast act ----
        {
            float pre[4];
#pragma unroll
            for (int q = 0; q < 4; ++q) pre[q] = gatesT[g][q * 16 + cc][m0] + fmaf(sv0, wib[q], bb[q]);
            float ig = fsig(pre[0]);
            float fg = fsig(pre[1]);
            float gg2 = ftanh(pre[2]);
            float og = fsig(pre[3]);
            cr0 = fg * cr0 + ig * gg2;
            float hv = og * ftanh(cr0);
            u16 hb = f2bf(hv);
            size_t ci = (size_t)b0 * H + kcol;
            hoh[ci] = hb;
            hol[ci] = f2bf(hv - bf2f(hb));
        }
        {
            float pre[4];
#pragma unroll
            for (int q = 0; q < 4; ++q) pre[q] = gatesT[g][q * 16 + cc][m0 + 16] + fmaf(sv1, wib[q], bb[q]);
            float ig = fsig(pre[0]);
            float fg = fsig(pre[1]);
            float gg2 = ftanh(pre[2]);
            float og = fsig(pre[3]);
            cr1 = fg * cr1 + ig * gg2;
            float hv = og * ftanh(cr1);
            u16 hb = f2bf(hv);
            size_t ci = (size_t)b1 * H + kcol;
            hoh[ci] = hb;
            hol[ci] = f2bf(hv - bf2f(hb));
        }

        // ---- per-GROUP XCD barrier (v13 protocol; skip after last step) ----
        if (t < T - 1) {
            asm volatile("s_waitcnt vmcnt(0)" ::: "memory");  // own h stores in L2
            group_barrier(gb, kh, l, base + 5);               // group drained
            if (kh == 0 && l == 0) {
                __hip_atomic_fetch_add(arrp, 1, __ATOMIC_RELAXED,
                                       __HIP_MEMORY_SCOPE_AGENT);
                const int target = 32 * (t + 1);
                int guard = 0;
                while (__hip_atomic_load(arrp, __ATOMIC_RELAXED,
                                         __HIP_MEMORY_SCOPE_AGENT) < target) {
                    __builtin_amdgcn_s_sleep(1);
                    if (++guard > (1 << 18)) break;           // tripwire
                }
                __hip_atomic_store(&grel[g], t + 1, __ATOMIC_RELEASE,
                                   __HIP_MEMORY_SCOPE_WORKGROUP);
            }
            {
                int guard = 0;
                while (__hip_atomic_load(&grel[g], __ATOMIC_ACQUIRE,
                                         __HIP_MEMORY_SCOPE_WORKGROUP) < t + 1) {
                    if (++guard > (1 << 17)) break;           // tripwire
                }
            }
            asm volatile("buffer_inv sc0" ::: "memory");      // invalidate L1 only
        }
    }
}

// ---------------------------------------------------------------------------
// MLP head
// ---------------------------------------------------------------------------
__global__ __launch_bounds__(256) void head_kernel(const u16* __restrict__ hhi,
                                                   const u16* __restrict__ hlo,
                                                   const float* __restrict__ fc1w,
                                                   const float* __restrict__ fc1b,
                                                   const float* __restrict__ fc2w,
                                                   const float* __restrict__ fc2b,
                                                   float* __restrict__ out) {
    const int b = blockIdx.x;
    const int tid = threadIdx.x;
    __shared__ __align__(16) float hb[H];
    __shared__ float z[256];

    hb[tid]       = bf2f(hhi[(size_t)b * H + tid])       + bf2f(hlo[(size_t)b * H + tid]);
    hb[tid + 256] = bf2f(hhi[(size_t)b * H + tid + 256]) + bf2f(hlo[(size_t)b * H + tid + 256]);
    __syncthreads();

    float acc = fc1b[tid];
    const float4* wr = (const float4*)(fc1w + (size_t)tid * H);
    const float4* hr = (const float4*)hb;
#pragma unroll 4
    for (int kk = 0; kk < H / 4; ++kk) {
        float4 wv = wr[kk], hv = hr[kk];
        acc += wv.x * hv.x + wv.y * hv.y + wv.z * hv.z + wv.w * hv.w;
    }
    z[tid] = fmaxf(acc, 0.0f);
    __syncthreads();

    if (tid < TGT) {
        float a = fc2b[tid];
        const float* w2 = fc2w + (size_t)tid * 256;
#pragma unroll 8
        for (int j = 0; j < 256; ++j) a += z[j] * w2[j];
        out[(size_t)b * TGT + tid] = a;
    }
}

extern "C" void kernel_launch(void* const* d_in, const int* in_sizes, int n_in,
                              void* d_out, int out_size, void* d_ws, size_t ws_size,
                              hipStream_t stream) {
    const float* seq  = (const float*)d_in[0];
    const float* Wih  = (const float*)d_in[1];
    const float* Whh  = (const float*)d_in[2];
    const float* bih  = (const float*)d_in[3];
    const float* bhh  = (const float*)d_in[4];
    const float* fc1w = (const float*)d_in[5];
    const float* fc1b = (const float*)d_in[6];
    const float* fc2w = (const float*)d_in[7];
    const float* fc2b = (const float*)d_in[8];
    float* out = (float*)d_out;

    char* wsb = (char*)d_ws;
    u16* wph  = (u16*)(wsb + OFF_WPH);
    u16* wpl  = (u16*)(wsb + OFF_WPL);
    u16* hhi0 = (u16*)(wsb + OFF_HHI0);
    u16* hlo0 = (u16*)(wsb + OFF_HLO0);
    u16* hhi1 = (u16*)(wsb + OFF_HHI1);
    u16* hlo1 = (u16*)(wsb + OFF_HLO1);
    int* sync = (int*)(wsb + OFF_SYNC);

    init_pack<<<512, 256, 0, stream>>>(Whh, wph, wpl);
    init_state<<<1028, 256, 0, stream>>>((unsigned*)(wsb + OFF_HHI0));

    hipFuncSetAttribute((const void*)lstm_persistent,
                        hipFuncAttributeMaxDynamicSharedMemorySize, SMEM_BYTES);

    void* args[] = {(void*)&wph, (void*)&wpl, (void*)&hhi0, (void*)&hlo0,
                    (void*)&hhi1, (void*)&hlo1, (void*)&sync, (void*)&seq,
                    (void*)&Wih, (void*)&bih, (void*)&bhh};
    // proven launch shape: 256 WGs x 512 thr, 1 WG/CU
    hipLaunchCooperativeKernel((const void*)lstm_persistent, dim3(256), dim3(512),
                               args, SMEM_BYTES, stream);

    // T even -> final h in buffer 0
    head_kernel<<<B, 256, 0, stream>>>(hhi0, hlo0, fc1w, fc1b, fc2w, fc2b, out);
}